// Round 1
// baseline (2004.650 us; speedup 1.0000x reference)
//
#include <hip/hip_runtime.h>

#define B_ 4
#define C_ 64
#define H_ 128
#define W_ 128
#define NPIX (H_*W_)           // 16384
#define NTOT (B_*C_*NPIX)      // 4194304
#define NOFF (B_*18*NPIX)      // 1179648
#define EPS_ 1e-5f

// ---------------- K1: offset conv 3x3, Cin=64 -> Cout=18, pad 1 ----------------
__global__ __launch_bounds__(256) void offset_conv_kernel(
    const float* __restrict__ x, const float* __restrict__ ow,
    const float* __restrict__ ob, float* __restrict__ off)
{
    __shared__ float xt[8*324];   // 8 ci x 18 x 18 halo tile
    __shared__ float wt[72*18];   // (ci,k) x 18 co
    const int t = threadIdx.x;
    const int bid = blockIdx.x;
    const int xtile = bid & 7, ytile = (bid>>3)&7, b = bid>>6;
    const int x0 = xtile*16, y0 = ytile*16;
    const int tx = t & 15, ty = t >> 4;

    float acc[18];
#pragma unroll
    for (int o=0;o<18;o++) acc[o]=0.f;

    for (int ci0=0; ci0<64; ci0+=8) {
        __syncthreads();
        // stage weights: wt[(c*9+k)*18+o] = ow[o][ci0+c][k]
        for (int i=t;i<1296;i+=256) {
            int o = i/72, rem = i%72;
            wt[rem*18+o] = ow[o*576 + ci0*9 + rem];
        }
        // stage x halo tile (zero pad)
        for (int i=t;i<2592;i+=256) {
            int c = i/324, p = i%324;
            int yy = p/18, xx = p%18;
            int gy = y0+yy-1, gx = x0+xx-1;
            float v = 0.f;
            if (gy>=0 && gy<H_ && gx>=0 && gx<W_)
                v = x[(((b<<6)+(ci0+c))<<14) + gy*W_ + gx];
            xt[i] = v;
        }
        __syncthreads();
#pragma unroll
        for (int c=0;c<8;c++) {
#pragma unroll
            for (int k=0;k<9;k++) {
                int kh=k/3, kw=k-kh*3;
                float xv = xt[c*324 + (ty+kh)*18 + (tx+kw)];
#pragma unroll
                for (int o=0;o<18;o++)
                    acc[o] += xv * wt[(c*9+k)*18 + o];
            }
        }
    }
#pragma unroll
    for (int o=0;o<18;o++)
        off[((b*18+o)<<14) + (y0+ty)*W_ + (x0+tx)] = acc[o] + ob[o];
}

// ---------------- K2: deformable conv, Cin=Cout=64, K=3 ----------------
// Block: 64 pixels = 2 rows x 32 cols, 256 threads. Grid: 4 wtiles * 64 htiles * 4 b = 1024.
__global__ __launch_bounds__(256) void deform_kernel(
    const float* __restrict__ x, const float* __restrict__ off,
    const float* __restrict__ dw, float* __restrict__ y)
{
    __shared__ __align__(16) float slds[72*64];   // sampled[(cil*9+kk)][pix]
    __shared__ __align__(16) float wlds[72*68];   // w[(cil*9+kk)][co], row stride 68
    __shared__ int   pa[4][576];                  // corner plane offsets per (kk,pix)
    __shared__ float pw[4][576];                  // corner bilinear weights

    const int t = threadIdx.x;
    const int bid = blockIdx.x;
    const int wtile = bid & 3, htile = (bid>>2)&63, b = bid>>8;
    const int w0 = wtile*32, h0 = htile*2;

    // ---- precompute sampling positions for all 9 kk x 64 pix ----
    for (int p=t; p<576; p+=256) {
        int kk = p>>6, pix = p&63;
        int r = pix>>5, c = pix&31;
        int h = h0 + r, wc = w0 + c;
        int kh = kk/3, kw = kk - kh*3;
        float dy = off[((b*18 + 2*kk  )<<14) + h*W_ + wc];
        float dx = off[((b*18 + 2*kk+1)<<14) + h*W_ + wc];
        float py = dy + (float)(h - 1 + kh);
        float px = dx + (float)(wc - 1 + kw);
        float fy = floorf(py), fx = floorf(px);
        float ly = py - fy, lx = px - fx;
        int y0i = (int)fy, x0i = (int)fx;
        int y1i = y0i+1, x1i = x0i+1;
        float vy0 = (y0i>=0 && y0i<H_) ? 1.f : 0.f;
        float vy1 = (y1i>=0 && y1i<H_) ? 1.f : 0.f;
        float vx0 = (x0i>=0 && x0i<W_) ? 1.f : 0.f;
        float vx1 = (x1i>=0 && x1i<W_) ? 1.f : 0.f;
        int y0c = min(max(y0i,0),H_-1), y1c = min(max(y1i,0),H_-1);
        int x0c = min(max(x0i,0),W_-1), x1c = min(max(x1i,0),W_-1);
        pa[0][p] = y0c*W_ + x0c;
        pa[1][p] = y0c*W_ + x1c;
        pa[2][p] = y1c*W_ + x0c;
        pa[3][p] = y1c*W_ + x1c;
        pw[0][p] = (1.f-ly)*(1.f-lx)*vy0*vx0;
        pw[1][p] = (1.f-ly)*lx*vy0*vx1;
        pw[2][p] = ly*(1.f-lx)*vy1*vx0;
        pw[3][p] = ly*lx*vy1*vx1;
    }

    const int pix  = t & 63;
    const int cihi = t >> 6;            // 0..3
    const int pix0 = (t & 15) * 4;      // phase B: 4 consecutive pixels
    const int co0  = (t >> 4) * 4;      // phase B: 4 consecutive out channels

    float acc[4][4];
#pragma unroll
    for (int j=0;j<4;j++)
#pragma unroll
        for (int u=0;u<4;u++) acc[j][u]=0.f;

    for (int ci0=0; ci0<64; ci0+=8) {
        __syncthreads();   // posbuf ready / previous phase B done
        // stage weights: wlds[idx][co] = dw[co][ci0..ci0+7][kk]
        for (int i=t;i<4608;i+=256) {
            int idx = i%72, co = i/72;
            wlds[idx*68+co] = dw[co*576 + ci0*9 + idx];
        }
        // phase A: bilinear sampling into slds
        for (int kk=0;kk<9;kk++) {
            int p = (kk<<6) + pix;
            int a00=pa[0][p], a01=pa[1][p], a10=pa[2][p], a11=pa[3][p];
            float w00=pw[0][p], w01=pw[1][p], w10=pw[2][p], w11=pw[3][p];
#pragma unroll
            for (int it=0; it<2; it++) {
                int cil = cihi + (it<<2);
                const float* xp = x + (((b<<6) + ci0 + cil)<<14);
                float v = w00*xp[a00] + w01*xp[a01] + w10*xp[a10] + w11*xp[a11];
                slds[(cil*9+kk)*64 + pix] = v;
            }
        }
        __syncthreads();
        // phase B: outer-product accumulate
#pragma unroll 4
        for (int idx=0; idx<72; idx++) {
            float4 sv = *(const float4*)&slds[idx*64 + pix0];
            float4 wv = *(const float4*)&wlds[idx*68 + co0];
            acc[0][0] += sv.x*wv.x; acc[0][1] += sv.x*wv.y; acc[0][2] += sv.x*wv.z; acc[0][3] += sv.x*wv.w;
            acc[1][0] += sv.y*wv.x; acc[1][1] += sv.y*wv.y; acc[1][2] += sv.y*wv.z; acc[1][3] += sv.y*wv.w;
            acc[2][0] += sv.z*wv.x; acc[2][1] += sv.z*wv.y; acc[2][2] += sv.z*wv.z; acc[2][3] += sv.z*wv.w;
            acc[3][0] += sv.w*wv.x; acc[3][1] += sv.w*wv.y; acc[3][2] += sv.w*wv.z; acc[3][3] += sv.w*wv.w;
        }
    }

    const int r = pix0 >> 5, c0 = pix0 & 31;
#pragma unroll
    for (int u=0;u<4;u++) {
        float4 st = make_float4(acc[0][u],acc[1][u],acc[2][u],acc[3][u]);
        *(float4*)&y[(((b<<6)+co0+u)<<14) + (h0+r)*W_ + w0 + c0] = st;
    }
}

// ---------------- K3: per-channel mean/var -> scale/shift ----------------
__global__ __launch_bounds__(256) void stats_kernel(
    const float* __restrict__ y, const float* __restrict__ gamma,
    const float* __restrict__ beta, float* __restrict__ stats)
{
    const int co = blockIdx.x, t = threadIdx.x;
    float s=0.f, s2=0.f;
    for (int b=0;b<4;b++) {
        const float* p = y + (((b<<6)+co)<<14);
        for (int i=t;i<NPIX;i+=256) { float v=p[i]; s+=v; s2+=v*v; }
    }
    __shared__ float rs[256], rs2[256];
    rs[t]=s; rs2[t]=s2; __syncthreads();
    for (int k=128;k>0;k>>=1) {
        if (t<k){ rs[t]+=rs[t+k]; rs2[t]+=rs2[t+k]; }
        __syncthreads();
    }
    if (t==0) {
        float mean = rs[0] * (1.f/65536.f);
        float var  = rs2[0] * (1.f/65536.f) - mean*mean;
        float inv  = rsqrtf(var + EPS_);
        float sc   = gamma[co]*inv;
        stats[co]    = sc;
        stats[64+co] = beta[co] - mean*sc;
    }
}

// ---------------- K4: normalize + ReLU + epilogue ----------------
// mode 0: out = relu(...)   mode 1: out = relu(...) + addsrc   mode 2: out += relu(...)
__global__ __launch_bounds__(256) void norm_kernel(
    const float* __restrict__ y, const float* __restrict__ stats,
    const float* __restrict__ addsrc, float* out, int mode)
{
    const int i4 = blockIdx.x*256 + threadIdx.x;   // N/4 = 1048576 total
    const int ch = (i4 >> 12) & 63;
    const float sc = stats[ch], sh = stats[64+ch];
    float4 v = *(const float4*)&y[i4*4];
    float4 r;
    r.x = fmaxf(v.x*sc+sh, 0.f);
    r.y = fmaxf(v.y*sc+sh, 0.f);
    r.z = fmaxf(v.z*sc+sh, 0.f);
    r.w = fmaxf(v.w*sc+sh, 0.f);
    if (mode == 1) {
        float4 a = *(const float4*)&addsrc[i4*4];
        r.x+=a.x; r.y+=a.y; r.z+=a.z; r.w+=a.w;
    } else if (mode == 2) {
        float4 o = *(const float4*)&out[i4*4];
        r.x+=o.x; r.y+=o.y; r.z+=o.z; r.w+=o.w;
    }
    *(float4*)&out[i4*4] = r;
}

// ---------------- host orchestration ----------------
static void run_layer(int li,
                      const float* in, float* outbuf, int mode, const float* addsrc,
                      const float* ow, const float* ob, const float* dw,
                      const float* g, const float* be,
                      float* offbuf, float* ybuf, float* stats, hipStream_t stream)
{
    const float* ow_l = ow + (size_t)li*18*64*9;
    const float* ob_l = ob + (size_t)li*18;
    const float* dw_l = dw + (size_t)li*64*64*9;
    const float* g_l  = g  + (size_t)li*64;
    const float* be_l = be + (size_t)li*64;

    offset_conv_kernel<<<256, 256, 0, stream>>>(in, ow_l, ob_l, offbuf);
    deform_kernel<<<1024, 256, 0, stream>>>(in, offbuf, dw_l, ybuf);
    stats_kernel<<<64, 256, 0, stream>>>(ybuf, g_l, be_l, stats);
    norm_kernel<<<4096, 256, 0, stream>>>(ybuf, stats, addsrc, outbuf, mode);
}

extern "C" void kernel_launch(void* const* d_in, const int* in_sizes, int n_in,
                              void* d_out, int out_size, void* d_ws, size_t ws_size,
                              hipStream_t stream)
{
    const float* x  = (const float*)d_in[0];
    const float* ow = (const float*)d_in[1];
    const float* ob = (const float*)d_in[2];
    const float* dw = (const float*)d_in[3];
    const float* g  = (const float*)d_in[4];
    const float* be = (const float*)d_in[5];
    float* out = (float*)d_out;

    float* t0    = (float*)d_ws;
    float* t1    = t0 + NTOT;
    float* ybuf  = t1 + NTOT;
    float* offb  = ybuf + NTOT;
    float* stats = offb + NOFF;

    // out_1 = L(1, L(0, x))
    run_layer(0, x,  t0, 0, nullptr, ow, ob, dw, g, be, offb, ybuf, stats, stream);
    run_layer(1, t0, t1, 0, nullptr, ow, ob, dw, g, be, offb, ybuf, stats, stream);
    // out_sum_1 = out_1 + L(4, x)   -> t0
    run_layer(4, x,  t0, 1, t1,      ow, ob, dw, g, be, offb, ybuf, stats, stream);
    // out_1' = L(3, L(2, s))
    run_layer(2, t0, t1, 0, nullptr, ow, ob, dw, g, be, offb, ybuf, stats, stream);
    run_layer(3, t1, out, 0, nullptr, ow, ob, dw, g, be, offb, ybuf, stats, stream);
    // += L(5, s), += L(6, s)
    run_layer(5, t0, out, 2, nullptr, ow, ob, dw, g, be, offb, ybuf, stats, stream);
    run_layer(6, t0, out, 2, nullptr, ow, ob, dw, g, be, offb, ybuf, stats, stream);
}